// Round 5
// baseline (565.009 us; speedup 1.0000x reference)
//
#include <hip/hip_runtime.h>
#include <hip/hip_bf16.h>

typedef __bf16 bf16x8 __attribute__((ext_vector_type(8)));
typedef float f32x4 __attribute__((ext_vector_type(4)));
typedef __hip_bfloat16 bf16;

#define NTOK 1569

__device__ __forceinline__ void gl_lds16(const void* g, void* l) {
  __builtin_amdgcn_global_load_lds(
      (const __attribute__((address_space(1))) void*)g,
      (__attribute__((address_space(3))) void*)l, 16, 0, 0);
}

__device__ __forceinline__ unsigned short bf16bits(float v) {
  union { __hip_bfloat16 h; unsigned short u; } cv;
  cv.h = __float2bfloat16(v);
  return cv.u;
}

// ---------------- f32 -> bf16 convert (vectorized) ----------------
__global__ void cvt_bf16_k(const float4* __restrict__ src, uint2* __restrict__ dst, int n4) {
  int i = blockIdx.x * 256 + threadIdx.x;
  if (i < n4) {
    float4 v = src[i];
    union { unsigned short h[4]; uint2 u; } pk;
    pk.h[0] = bf16bits(v.x); pk.h[1] = bf16bits(v.y);
    pk.h[2] = bf16bits(v.z); pk.h[3] = bf16bits(v.w);
    dst[i] = pk.u;
  }
}

// transpose-convert: dst[c][r] = src[r][c], 768x768
__global__ void cvt_t_k(const float* __restrict__ src, bf16* __restrict__ dst) {
  int idx = blockIdx.x * 256 + threadIdx.x;
  int r = idx / 768, c = idx % 768;
  dst[(size_t)c * 768 + r] = __float2bfloat16(src[idx]);
}

// bcomb[j] = sum_i Wf[j][i]*bp[i] + bf[j]
__global__ __launch_bounds__(256) void bcomb_k(const float* __restrict__ Wf,
                                               const float* __restrict__ bp,
                                               const float* __restrict__ bfv,
                                               float* __restrict__ out) {
  int j = blockIdx.x * 4 + (threadIdx.x >> 6);
  int l = threadIdx.x & 63;
  if (j >= 768) return;
  float s = 0.f;
#pragma unroll
  for (int u = 0; u < 12; ++u) s += Wf[(size_t)j * 768 + l + 64 * u] * bp[l + 64 * u];
#pragma unroll
  for (int o = 1; o < 64; o <<= 1) s += __shfl_xor(s, o);
  if (l == 0) out[j] = s + bfv[j];
}

// ---------------- LayerNorm (float4 vectorized) ----------------
__global__ __launch_bounds__(256) void ln_k(
    const float* __restrict__ xsrc, const float* __restrict__ xt,
    const float* __restrict__ gam, const float* __restrict__ bet,
    bf16* __restrict__ y, int M, int mode) {
  int r = blockIdx.x * 4 + (threadIdx.x >> 6);
  int l = threadIdx.x & 63;
  if (r >= M) return;
  const float* src;
  if (mode == 0) {
    src = xsrc + (size_t)(r + r / 1568 + 1) * 768;
  } else {
    int g = r / 197, j = r % 197;
    int b = g >> 3, t = g & 7;
    if (j == 0) src = xsrc + (size_t)b * NTOK * 768;
    else        src = xt + (size_t)(b * 1568 + (j - 1) * 8 + t) * 768;
  }
  const float4* s4 = (const float4*)src;
  const float4* g4 = (const float4*)gam;
  const float4* b4 = (const float4*)bet;
  float4 v[3]; float s = 0.f, s2 = 0.f;
#pragma unroll
  for (int u = 0; u < 3; ++u) {
    float4 t4 = s4[l + 64 * u];
    v[u] = t4;
    s += t4.x + t4.y + t4.z + t4.w;
    s2 += t4.x * t4.x + t4.y * t4.y + t4.z * t4.z + t4.w * t4.w;
  }
#pragma unroll
  for (int o = 1; o < 64; o <<= 1) { s += __shfl_xor(s, o); s2 += __shfl_xor(s2, o); }
  float mu = s * (1.f / 768.f);
  float rstd = rsqrtf(s2 * (1.f / 768.f) - mu * mu + 1e-5f);
  uint2* yr = (uint2*)(y + (size_t)r * 768);
#pragma unroll
  for (int u = 0; u < 3; ++u) {
    int j = l + 64 * u;
    float4 gg = g4[j], bb = b4[j];
    union { unsigned short h[4]; uint2 u2; } pk;
    pk.h[0] = bf16bits((v[u].x - mu) * rstd * gg.x + bb.x);
    pk.h[1] = bf16bits((v[u].y - mu) * rstd * gg.y + bb.y);
    pk.h[2] = bf16bits((v[u].z - mu) * rstd * gg.z + bb.z);
    pk.h[3] = bf16bits((v[u].w - mu) * rstd * gg.w + bb.w);
    yr[j] = pk.u2;
  }
}

// ---------------- fused combine + LN2 ----------------
__global__ __launch_bounds__(256) void combine_ln_k(
    const float* __restrict__ x, const float* __restrict__ xt,
    const float* __restrict__ rs, const float* __restrict__ gam,
    const float* __restrict__ bet, float* __restrict__ xn,
    bf16* __restrict__ y) {
  int r = blockIdx.x * 4 + (threadIdx.x >> 6);
  int l = threadIdx.x & 63;
  if (r >= 4 * NTOK) return;
  int b = r / NTOK, n = r % NTOK;
  float4 v[3]; float s = 0.f, s2 = 0.f;
  if (n == 0) {
#pragma unroll
    for (int u = 0; u < 3; ++u) {
      int j = l + 64 * u;
      float4 a = {0.f, 0.f, 0.f, 0.f};
#pragma unroll
      for (int t = 0; t < 8; ++t) {
        float4 rv = ((const float4*)(rs + (size_t)((b * 8 + t) * 197) * 768))[j];
        a.x += rv.x; a.y += rv.y; a.z += rv.z; a.w += rv.w;
      }
      float4 xv = ((const float4*)(x + (size_t)r * 768))[j];
      v[u].x = xv.x + a.x * 0.125f; v[u].y = xv.y + a.y * 0.125f;
      v[u].z = xv.z + a.z * 0.125f; v[u].w = xv.w + a.w * 0.125f;
    }
  } else {
    int hw = (n - 1) >> 3, t = (n - 1) & 7;
    const float4* xt4 = (const float4*)(xt + (size_t)(b * 1568 + n - 1) * 768);
    const float4* rs4 = (const float4*)(rs + (size_t)((b * 8 + t) * 197 + 1 + hw) * 768);
#pragma unroll
    for (int u = 0; u < 3; ++u) {
      int j = l + 64 * u;
      float4 a = xt4[j], c = rs4[j];
      v[u].x = a.x + c.x; v[u].y = a.y + c.y; v[u].z = a.z + c.z; v[u].w = a.w + c.w;
    }
  }
  float4* xn4 = (float4*)(xn + (size_t)r * 768);
#pragma unroll
  for (int u = 0; u < 3; ++u) {
    xn4[l + 64 * u] = v[u];
    s += v[u].x + v[u].y + v[u].z + v[u].w;
    s2 += v[u].x * v[u].x + v[u].y * v[u].y + v[u].z * v[u].z + v[u].w * v[u].w;
  }
#pragma unroll
  for (int o = 1; o < 64; o <<= 1) { s += __shfl_xor(s, o); s2 += __shfl_xor(s2, o); }
  float mu = s * (1.f / 768.f);
  float rstd = rsqrtf(s2 * (1.f / 768.f) - mu * mu + 1e-5f);
  const float4* g4 = (const float4*)gam;
  const float4* b4 = (const float4*)bet;
  uint2* yr = (uint2*)(y + (size_t)r * 768);
#pragma unroll
  for (int u = 0; u < 3; ++u) {
    int j = l + 64 * u;
    float4 gg = g4[j], bb = b4[j];
    union { unsigned short h[4]; uint2 u2; } pk;
    pk.h[0] = bf16bits((v[u].x - mu) * rstd * gg.x + bb.x);
    pk.h[1] = bf16bits((v[u].y - mu) * rstd * gg.y + bb.y);
    pk.h[2] = bf16bits((v[u].z - mu) * rstd * gg.z + bb.z);
    pk.h[3] = bf16bits((v[u].w - mu) * rstd * gg.w + bb.w);
    yr[j] = pk.u2;
  }
}

// ============ GEMM 128x128, BK=32, ring-3 LDS, ONE barrier/step, counted vmcnt ============
template <int OUTBF16, int RES, int GELU>
__global__ __launch_bounds__(256, 3) void gemm_k(
    const bf16* __restrict__ X, const bf16* __restrict__ W,
    const float* __restrict__ bias, const float* __restrict__ resid,
    void* __restrict__ outp, int M, int N, int K) {
  constexpr int BUFB = 256 * 64;                 // 16 KB per K-tile buffer
  __shared__ __align__(16) char LDS[3 * BUFB];   // 48 KB -> 3 blocks/CU
  const int tid = threadIdx.x;
  const int w = tid >> 6, l = tid & 63;
  const int wr = w >> 1, wc = w & 1;
  const int lr = l & 15, lg = l >> 4;

  // bijective XCD-aware tile swizzle (m204)
  const int nwg = gridDim.x;
  const int orig = blockIdx.x;
  const int qd = nwg >> 3, rm = nwg & 7;
  const int xcd = orig & 7, lot = orig >> 3;
  const int swz = (xcd < rm ? xcd * (qd + 1) : rm * (qd + 1) + (xcd - rm) * qd) + lot;
  const int ntx = N >> 7;
  const int m0 = (swz / ntx) << 7, n0 = (swz % ntx) << 7;

  // per-thread staging source pointers (advance +64B per K-tile)
  const char* pA[2]; const char* pB[2]; int dd[2];
#pragma unroll
  for (int i = 0; i < 2; ++i) {
    int d = (i * 256 + tid) * 16;
    int s = d ^ (((d >> 7) & 3) << 4);           // inverse swizzle on source
    int r = s >> 6, cb = s & 63;
    int ga = m0 + r; if (ga >= M) ga = M - 1;    // clamp ragged M (A only)
    pA[i] = (const char*)X + (size_t)ga * K * 2 + cb;
    pB[i] = (const char*)W + (size_t)(n0 + r) * K * 2 + cb;
    dd[i] = d;
  }

  auto stage = [&](int t, char* buf) {
    size_t ko = (size_t)t * 64;
    gl_lds16(pA[0] + ko, buf + dd[0]);
    gl_lds16(pA[1] + ko, buf + dd[1]);
    gl_lds16(pB[0] + ko, buf + 8192 + dd[0]);
    gl_lds16(pB[1] + ko, buf + 8192 + dd[1]);
  };

  f32x4 acc[4][4] = {};
  auto comp = [&](const char* Ab) {
    const char* Bb = Ab + 8192;
    bf16x8 af[4], bg[4];
#pragma unroll
    for (int mf = 0; mf < 4; ++mf) {
      int d = (wr * 64 + mf * 16 + lr) * 64 + lg * 16;
      af[mf] = *(const bf16x8*)(Ab + (d ^ (((d >> 7) & 3) << 4)));
    }
#pragma unroll
    for (int nf = 0; nf < 4; ++nf) {
      int d = (wc * 64 + nf * 16 + lr) * 64 + lg * 16;
      bg[nf] = *(const bf16x8*)(Bb + (d ^ (((d >> 7) & 3) << 4)));
    }
    __builtin_amdgcn_s_setprio(1);
#pragma unroll
    for (int mf = 0; mf < 4; ++mf)
#pragma unroll
      for (int nf = 0; nf < 4; ++nf)
        acc[mf][nf] = __builtin_amdgcn_mfma_f32_16x16x32_bf16(af[mf], bg[nf], acc[mf][nf], 0, 0, 0);
    __builtin_amdgcn_s_setprio(0);
  };

  const int nt = K >> 5;                         // all K used: nt % 3 == 0
  stage(0, LDS);
  stage(1, LDS + BUFB);
  asm volatile("s_waitcnt vmcnt(4)\n\ts_barrier" ::: "memory");
  int t = 0;
#define GSTEP(BC, BS)                                                                      \
  {                                                                                        \
    if (t + 2 < nt) stage(t + 2, LDS + (BS) * BUFB);                                       \
    comp(LDS + (BC) * BUFB);                                                               \
    if (t + 2 < nt)                                                                        \
      asm volatile("s_waitcnt vmcnt(4)\n\ts_barrier" ::: "memory");                        \
    else if (t + 1 < nt)                                                                   \
      asm volatile("s_waitcnt vmcnt(0)\n\ts_barrier" ::: "memory");                        \
    ++t;                                                                                   \
  }
  while (t < nt) { GSTEP(0, 2) GSTEP(1, 0) GSTEP(2, 1) }
#undef GSTEP

#pragma unroll
  for (int mf = 0; mf < 4; ++mf) {
    int rowb = m0 + wr * 64 + mf * 16 + lg * 4;
#pragma unroll
    for (int nf = 0; nf < 4; ++nf) {
      int col = n0 + wc * 64 + nf * 16 + lr;
      float bv = bias ? bias[col] : 0.f;
#pragma unroll
      for (int q = 0; q < 4; ++q) {
        int row = rowb + q;
        if (row < M) {
          float v = acc[mf][nf][q] + bv;
          if (GELU) v = 0.5f * v * (1.f + erff(v * 0.70710678118654752f));
          if (RES == 1) v += resid[(size_t)(row + row / 1568 + 1) * 768 + col];
          if (RES == 2) v += resid[(size_t)row * N + col];
          if (OUTBF16) ((bf16*)outp)[(size_t)row * N + col] = __float2bfloat16(v);
          else         ((float*)outp)[(size_t)row * N + col] = v;
        }
      }
    }
  }
}

// ---------------- temporal attention: 784 seqs x 12 heads, T=8, D=64 ----------------
__global__ __launch_bounds__(256) void attn_t_k(const bf16* __restrict__ qkv,
                                                bf16* __restrict__ outp) {
  __shared__ float sh[4][3 * 8 * 68];   // q,k,v each [8][68]
  const int wv = threadIdx.x >> 6, l = threadIdx.x & 63;
  const int g = blockIdx.x * 4 + wv;
  const int sq = g / 12, hd = g % 12;
  float* qs = sh[wv];
  float* ks = qs + 544;
  float* vs = qs + 1088;
  const bf16* base = qkv + (size_t)sq * 8 * 2304 + hd * 64;
  {
    int row = l >> 3, c8 = (l & 7) * 8;
    const bf16* rp = base + (size_t)row * 2304 + c8;
    bf16x8 qv = *(const bf16x8*)rp;
    bf16x8 kv = *(const bf16x8*)(rp + 768);
    bf16x8 vv = *(const bf16x8*)(rp + 1536);
    float* qd = qs + row * 68 + c8;
    float* kd = ks + row * 68 + c8;
    float* vd = vs + row * 68 + c8;
    float4 a, b;
    a.x = (float)qv[0]; a.y = (float)qv[1]; a.z = (float)qv[2]; a.w = (float)qv[3];
    b.x = (float)qv[4]; b.y = (float)qv[5]; b.z = (float)qv[6]; b.w = (float)qv[7];
    *(float4*)qd = a; *(float4*)(qd + 4) = b;
    a.x = (float)kv[0]; a.y = (float)kv[1]; a.z = (float)kv[2]; a.w = (float)kv[3];
    b.x = (float)kv[4]; b.y = (float)kv[5]; b.z = (float)kv[6]; b.w = (float)kv[7];
    *(float4*)kd = a; *(float4*)(kd + 4) = b;
    a.x = (float)vv[0]; a.y = (float)vv[1]; a.z = (float)vv[2]; a.w = (float)vv[3];
    b.x = (float)vv[4]; b.y = (float)vv[5]; b.z = (float)vv[6]; b.w = (float)vv[7];
    *(float4*)vd = a; *(float4*)(vd + 4) = b;
  }
  __builtin_amdgcn_wave_barrier();
  const int i = l >> 3, j = l & 7;
  float s = 0.f;
#pragma unroll
  for (int d = 0; d < 64; ++d) s += qs[i * 68 + d] * ks[j * 68 + d];
  s *= 0.125f;
  float m = s;
  m = fmaxf(m, __shfl_xor(m, 1));
  m = fmaxf(m, __shfl_xor(m, 2));
  m = fmaxf(m, __shfl_xor(m, 4));
  float p = __expf(s - m);
  float sum = p;
  sum += __shfl_xor(sum, 1);
  sum += __shfl_xor(sum, 2);
  sum += __shfl_xor(sum, 4);
  p /= sum;
  float pr[8];
#pragma unroll
  for (int jj = 0; jj < 8; ++jj) pr[jj] = __shfl(p, i * 8 + jj);
  bf16* op = outp + (size_t)(sq * 8) * 768 + hd * 64;
#pragma unroll
  for (int u = 0; u < 8; ++u) {
    int c = j + 8 * u;
    float o = 0.f;
#pragma unroll
    for (int jj = 0; jj < 8; ++jj) o += pr[jj] * vs[jj * 68 + c];
    op[(size_t)i * 768 + c] = __float2bfloat16(o);
  }
}

// ---------------- build Vt[384][64][224] from spatial qkv ----------------
__global__ __launch_bounds__(256) void build_vt_k(const bf16* __restrict__ qkv,
                                                  bf16* __restrict__ vt) {
  const int sq = blockIdx.x / 12, hd = blockIdx.x % 12;
  const bf16* vsrc = qkv + (size_t)sq * 197 * 2304 + 1536 + hd * 64;
  bf16* dst = vt + (size_t)blockIdx.x * 64 * 224;
  for (int idx = threadIdx.x; idx < 197 * 64; idx += 256) {
    int j = idx >> 6, d = idx & 63;
    dst[d * 224 + j] = vsrc[(size_t)j * 2304 + d];
  }
}

// ---------------- spatial attention: 32 seqs x 12 heads, N=197, D=64 ----------------
__global__ __launch_bounds__(256) void attn_s_k(
    const bf16* __restrict__ qkv, const bf16* __restrict__ vt,
    bf16* __restrict__ outp) {
  __shared__ __align__(16) bf16 P[4][16 * 232];
  const int wv = threadIdx.x >> 6, l = threadIdx.x & 63;
  const int sq = blockIdx.x / 12, hd = blockIdx.x % 12;
  const int lr = l & 15, lg = l >> 4;
  bf16* Pw = P[wv];
#pragma unroll
  for (int idx = 0; idx < 4; ++idx) {
    int e = idx * 64 + l;
    Pw[(e >> 4) * 232 + 208 + (e & 15)] = __float2bfloat16(0.f);
  }
  const bf16* qbase = qkv + (size_t)sq * 197 * 2304 + hd * 64;
  const bf16* kbase = qbase + 768;
  const bf16* vbase = vt + (size_t)blockIdx.x * 64 * 224;
  for (int qt = wv; qt < 13; qt += 4) {
    int q0 = qt * 16;
    int qrow = q0 + lr; if (qrow > 196) qrow = 196;
    bf16x8 qa0 = *(const bf16x8*)(qbase + (size_t)qrow * 2304 + lg * 8);
    bf16x8 qa1 = *(const bf16x8*)(qbase + (size_t)qrow * 2304 + 32 + lg * 8);
    f32x4 sacc[13];
#pragma unroll
    for (int jt = 0; jt < 13; ++jt) {
      const bf16* kp = kbase + (size_t)(jt * 16 + lr) * 2304;
      bf16x8 kb0 = *(const bf16x8*)(kp + lg * 8);
      bf16x8 kb1 = *(const bf16x8*)(kp + 32 + lg * 8);
      f32x4 z = {};
      z = __builtin_amdgcn_mfma_f32_16x16x32_bf16(qa0, kb0, z, 0, 0, 0);
      z = __builtin_amdgcn_mfma_f32_16x16x32_bf16(qa1, kb1, z, 0, 0, 0);
      sacc[jt] = z;
    }
#pragma unroll
    for (int jt = 0; jt < 13; ++jt) {
      bool valid = (jt * 16 + lr) < 197;
#pragma unroll
      for (int q = 0; q < 4; ++q)
        sacc[jt][q] = valid ? sacc[jt][q] * 0.125f : -3e38f;
    }
    float inv[4];
#pragma unroll
    for (int q = 0; q < 4; ++q) {
      float m = -3e38f;
#pragma unroll
      for (int jt = 0; jt < 13; ++jt) m = fmaxf(m, sacc[jt][q]);
      m = fmaxf(m, __shfl_xor(m, 1));
      m = fmaxf(m, __shfl_xor(m, 2));
      m = fmaxf(m, __shfl_xor(m, 4));
      m = fmaxf(m, __shfl_xor(m, 8));
      float ssum = 0.f;
#pragma unroll
      for (int jt = 0; jt < 13; ++jt) {
        float p = __expf(sacc[jt][q] - m);
        sacc[jt][q] = p;
        ssum += p;
      }
      ssum += __shfl_xor(ssum, 1);
      ssum += __shfl_xor(ssum, 2);
      ssum += __shfl_xor(ssum, 4);
      ssum += __shfl_xor(ssum, 8);
      inv[q] = 1.f / ssum;
    }
#pragma unroll
    for (int jt = 0; jt < 13; ++jt)
#pragma unroll
      for (int q = 0; q < 4; ++q)
        Pw[(lg * 4 + q) * 232 + jt * 16 + lr] = __float2bfloat16(sacc[jt][q]);
    __builtin_amdgcn_wave_barrier();
    f32x4 oacc[4] = {};
#pragma unroll
    for (int j7 = 0; j7 < 7; ++j7) {
      bf16x8 pa = *(const bf16x8*)(Pw + lr * 232 + j7 * 32 + lg * 8);
#pragma unroll
      for (int n = 0; n < 4; ++n) {
        bf16x8 vb = *(const bf16x8*)(vbase + (size_t)(n * 16 + lr) * 224 + j7 * 32 + lg * 8);
        oacc[n] = __builtin_amdgcn_mfma_f32_16x16x32_bf16(pa, vb, oacc[n], 0, 0, 0);
      }
    }
    __builtin_amdgcn_wave_barrier();
#pragma unroll
    for (int n = 0; n < 4; ++n)
#pragma unroll
      for (int q = 0; q < 4; ++q) {
        int orow = q0 + lg * 4 + q;
        if (orow < 197)
          outp[(size_t)(sq * 197 + orow) * 768 + hd * 64 + n * 16 + lr] =
              __float2bfloat16(oacc[n][q] * inv[q]);
      }
  }
}

extern "C" void kernel_launch(void* const* d_in, const int* in_sizes, int n_in,
                              void* d_out, int out_size, void* d_ws, size_t ws_size,
                              hipStream_t stream) {
  (void)in_sizes; (void)n_in; (void)out_size; (void)ws_size;
  const float* x        = (const float*)d_in[0];
  const float* ln_t_g   = (const float*)d_in[1];
  const float* ln_t_b   = (const float*)d_in[2];
  const float* t_qkv_w  = (const float*)d_in[3];
  const float* t_qkv_b  = (const float*)d_in[4];
  const float* t_proj_w = (const float*)d_in[5];
  const float* t_proj_b = (const float*)d_in[6];
  const float* t_fc_w   = (const float*)d_in[7];
  const float* t_fc_b   = (const float*)d_in[8];
  const float* ln1_g    = (const float*)d_in[9];
  const float* ln1_b    = (const float*)d_in[10];
  const float* s_qkv_w  = (const float*)d_in[11];
  const float* s_qkv_b  = (const float*)d_in[12];
  const float* s_proj_w = (const float*)d_in[13];
  const float* s_proj_b = (const float*)d_in[14];
  const float* ln2_g    = (const float*)d_in[15];
  const float* ln2_b    = (const float*)d_in[16];
  const float* fc1_w    = (const float*)d_in[17];
  const float* fc1_b    = (const float*)d_in[18];
  const float* fc2_w    = (const float*)d_in[19];
  const float* fc2_b    = (const float*)d_in[20];

  char* ws = (char*)d_ws;
  size_t o = 0;
  auto alloc = [&](size_t bytes) { size_t r = o; o += (bytes + 255) & ~(size_t)255; return r; };
  bf16* wqkvt  = (bf16*)(ws + alloc((size_t)2304 * 768 * 2));
  bf16* wqkvs  = (bf16*)(ws + alloc((size_t)2304 * 768 * 2));
  bf16* wprojs = (bf16*)(ws + alloc((size_t)768 * 768 * 2));
  bf16* wfct   = (bf16*)(ws + alloc((size_t)768 * 768 * 2));
  bf16* wpT    = (bf16*)(ws + alloc((size_t)768 * 768 * 2));
  bf16* wcomb  = (bf16*)(ws + alloc((size_t)768 * 768 * 2));
  float* bcomb = (float*)(ws + alloc((size_t)768 * 4));
  bf16* wfc1   = (bf16*)(ws + alloc((size_t)3072 * 768 * 2));
  bf16* wfc2   = (bf16*)(ws + alloc((size_t)768 * 3072 * 2));
  bf16* ybuf   = (bf16*)(ws + alloc((size_t)6400 * 768 * 2));
  char* big    = ws + alloc((size_t)6400 * 3072 * 2);      // qkv, later h1
  bf16* qkvb   = (bf16*)big;
  bf16* h1     = (bf16*)big;
  bf16* abuf   = (bf16*)(ws + alloc((size_t)6400 * 768 * 2));
  char* slotS  = ws + alloc((size_t)6304 * 768 * 4);       // vt / rs (disjoint lifetimes)
  bf16* vtb    = (bf16*)slotS;
  float* rsb   = (float*)slotS;
  float* xtb   = (float*)(ws + alloc((size_t)6272 * 768 * 4));
  float* xnb   = (float*)(ws + alloc((size_t)6276 * 768 * 4));

  // weights -> bf16 (+ transposed proj_t) and combined temporal proj*fc
  cvt_bf16_k<<<1728, 256, 0, stream>>>((const float4*)t_qkv_w, (uint2*)wqkvt, 442368);
  cvt_bf16_k<<<1728, 256, 0, stream>>>((const float4*)s_qkv_w, (uint2*)wqkvs, 442368);
  cvt_bf16_k<<<576, 256, 0, stream>>>((const float4*)s_proj_w, (uint2*)wprojs, 147456);
  cvt_bf16_k<<<576, 256, 0, stream>>>((const float4*)t_fc_w, (uint2*)wfct, 147456);
  cvt_t_k<<<2304, 256, 0, stream>>>(t_proj_w, wpT);
  cvt_bf16_k<<<2304, 256, 0, stream>>>((const float4*)fc1_w, (uint2*)wfc1, 589824);
  cvt_bf16_k<<<2304, 256, 0, stream>>>((const float4*)fc2_w, (uint2*)wfc2, 589824);
  bcomb_k<<<192, 256, 0, stream>>>(t_fc_w, t_proj_b, t_fc_b, bcomb);
  // Wcomb[j][k] = sum_i Wf[j][i] * Wp[i][k]
  gemm_k<1, 0, 0><<<36, 256, 0, stream>>>(wfct, wpT, nullptr, nullptr, wcomb, 768, 768, 768);

  // temporal branch
  ln_k<<<1568, 256, 0, stream>>>(x, nullptr, ln_t_g, ln_t_b, ybuf, 6272, 0);
  gemm_k<1, 0, 0><<<882, 256, 0, stream>>>(ybuf, wqkvt, t_qkv_b, nullptr, qkvb, 6272, 2304, 768);
  attn_t_k<<<2352, 256, 0, stream>>>(qkvb, abuf);
  gemm_k<0, 1, 0><<<294, 256, 0, stream>>>(abuf, wcomb, bcomb, x, xtb, 6272, 768, 768);

  // spatial branch
  ln_k<<<1576, 256, 0, stream>>>(x, xtb, ln1_g, ln1_b, ybuf, 6304, 1);
  gemm_k<1, 0, 0><<<900, 256, 0, stream>>>(ybuf, wqkvs, s_qkv_b, nullptr, qkvb, 6304, 2304, 768);
  build_vt_k<<<384, 256, 0, stream>>>(qkvb, vtb);
  attn_s_k<<<384, 256, 0, stream>>>(qkvb, vtb, abuf);
  gemm_k<0, 0, 0><<<300, 256, 0, stream>>>(abuf, wprojs, s_proj_b, nullptr, rsb, 6304, 768, 768);

  // combine residuals + LN2 (fused)
  combine_ln_k<<<1569, 256, 0, stream>>>(x, xtb, rsb, ln2_g, ln2_b, xnb, ybuf);

  // MLP
  gemm_k<1, 0, 1><<<1200, 256, 0, stream>>>(ybuf, wfc1, fc1_b, nullptr, h1, 6276, 3072, 768);
  gemm_k<0, 2, 0><<<300, 256, 0, stream>>>(h1, wfc2, fc2_b, xnb, (float*)d_out, 6276, 768, 3072);
}

// Round 7
// 540.638 us; speedup vs baseline: 1.0451x; 1.0451x over previous
//
#include <hip/hip_runtime.h>
#include <hip/hip_bf16.h>

typedef __bf16 bf16x8 __attribute__((ext_vector_type(8)));
typedef float f32x4 __attribute__((ext_vector_type(4)));
typedef __hip_bfloat16 bf16;

#define NTOK 1569

__device__ __forceinline__ void gl_lds16(const void* g, void* l) {
  __builtin_amdgcn_global_load_lds(
      (const __attribute__((address_space(1))) void*)g,
      (__attribute__((address_space(3))) void*)l, 16, 0, 0);
}

__device__ __forceinline__ unsigned short bf16bits(float v) {
  union { __hip_bfloat16 h; unsigned short u; } cv;
  cv.h = __float2bfloat16(v);
  return cv.u;
}

// ---------------- merged f32 -> bf16 convert over 6 weight tensors ----------------
struct CvtSeg { const float4* src; uint2* dst; int end; };  // end = cumulative n4
__global__ void cvt_all_k(CvtSeg s0, CvtSeg s1, CvtSeg s2, CvtSeg s3, CvtSeg s4, CvtSeg s5) {
  int i = blockIdx.x * 256 + threadIdx.x;
  CvtSeg s; int base = 0;
  if (i < s0.end) { s = s0; }
  else if (i < s1.end) { s = s1; base = s0.end; }
  else if (i < s2.end) { s = s2; base = s1.end; }
  else if (i < s3.end) { s = s3; base = s2.end; }
  else if (i < s4.end) { s = s4; base = s3.end; }
  else if (i < s5.end) { s = s5; base = s4.end; }
  else return;
  int j = i - base;
  float4 v = s.src[j];
  union { unsigned short h[4]; uint2 u; } pk;
  pk.h[0] = bf16bits(v.x); pk.h[1] = bf16bits(v.y);
  pk.h[2] = bf16bits(v.z); pk.h[3] = bf16bits(v.w);
  s.dst[j] = pk.u;
}

// transpose-convert: dst[c][r] = src[r][c], 768x768
__global__ void cvt_t_k(const float* __restrict__ src, bf16* __restrict__ dst) {
  int idx = blockIdx.x * 256 + threadIdx.x;
  int r = idx / 768, c = idx % 768;
  dst[(size_t)c * 768 + r] = __float2bfloat16(src[idx]);
}

// bcomb[j] = sum_i Wf[j][i]*bp[i] + bf[j]
__global__ __launch_bounds__(256) void bcomb_k(const float* __restrict__ Wf,
                                               const float* __restrict__ bp,
                                               const float* __restrict__ bfv,
                                               float* __restrict__ out) {
  int j = blockIdx.x * 4 + (threadIdx.x >> 6);
  int l = threadIdx.x & 63;
  if (j >= 768) return;
  float s = 0.f;
#pragma unroll
  for (int u = 0; u < 12; ++u) s += Wf[(size_t)j * 768 + l + 64 * u] * bp[l + 64 * u];
#pragma unroll
  for (int o = 1; o < 64; o <<= 1) s += __shfl_xor(s, o);
  if (l == 0) out[j] = s + bfv[j];
}

// ---------------- LayerNorm (float4 vectorized) ----------------
__global__ __launch_bounds__(256) void ln_k(
    const float* __restrict__ xsrc, const float* __restrict__ xt,
    const float* __restrict__ gam, const float* __restrict__ bet,
    bf16* __restrict__ y, int M, int mode) {
  int r = blockIdx.x * 4 + (threadIdx.x >> 6);
  int l = threadIdx.x & 63;
  if (r >= M) return;
  const float* src;
  if (mode == 0) {
    src = xsrc + (size_t)(r + r / 1568 + 1) * 768;
  } else {
    int g = r / 197, j = r % 197;
    int b = g >> 3, t = g & 7;
    if (j == 0) src = xsrc + (size_t)b * NTOK * 768;
    else        src = xt + (size_t)(b * 1568 + (j - 1) * 8 + t) * 768;
  }
  const float4* s4 = (const float4*)src;
  const float4* g4 = (const float4*)gam;
  const float4* b4 = (const float4*)bet;
  float4 v[3]; float s = 0.f, s2 = 0.f;
#pragma unroll
  for (int u = 0; u < 3; ++u) {
    float4 t4 = s4[l + 64 * u];
    v[u] = t4;
    s += t4.x + t4.y + t4.z + t4.w;
    s2 += t4.x * t4.x + t4.y * t4.y + t4.z * t4.z + t4.w * t4.w;
  }
#pragma unroll
  for (int o = 1; o < 64; o <<= 1) { s += __shfl_xor(s, o); s2 += __shfl_xor(s2, o); }
  float mu = s * (1.f / 768.f);
  float rstd = rsqrtf(s2 * (1.f / 768.f) - mu * mu + 1e-5f);
  uint2* yr = (uint2*)(y + (size_t)r * 768);
#pragma unroll
  for (int u = 0; u < 3; ++u) {
    int j = l + 64 * u;
    float4 gg = g4[j], bb = b4[j];
    union { unsigned short h[4]; uint2 u2; } pk;
    pk.h[0] = bf16bits((v[u].x - mu) * rstd * gg.x + bb.x);
    pk.h[1] = bf16bits((v[u].y - mu) * rstd * gg.y + bb.y);
    pk.h[2] = bf16bits((v[u].z - mu) * rstd * gg.z + bb.z);
    pk.h[3] = bf16bits((v[u].w - mu) * rstd * gg.w + bb.w);
    yr[j] = pk.u2;
  }
}

// ---------------- fused combine + LN2 ----------------
__global__ __launch_bounds__(256) void combine_ln_k(
    const float* __restrict__ x, const float* __restrict__ xt,
    const float* __restrict__ rs, const float* __restrict__ gam,
    const float* __restrict__ bet, float* __restrict__ xn,
    bf16* __restrict__ y) {
  int r = blockIdx.x * 4 + (threadIdx.x >> 6);
  int l = threadIdx.x & 63;
  if (r >= 4 * NTOK) return;
  int b = r / NTOK, n = r % NTOK;
  float4 v[3]; float s = 0.f, s2 = 0.f;
  if (n == 0) {
#pragma unroll
    for (int u = 0; u < 3; ++u) {
      int j = l + 64 * u;
      float4 a = {0.f, 0.f, 0.f, 0.f};
#pragma unroll
      for (int t = 0; t < 8; ++t) {
        float4 rv = ((const float4*)(rs + (size_t)((b * 8 + t) * 197) * 768))[j];
        a.x += rv.x; a.y += rv.y; a.z += rv.z; a.w += rv.w;
      }
      float4 xv = ((const float4*)(x + (size_t)r * 768))[j];
      v[u].x = xv.x + a.x * 0.125f; v[u].y = xv.y + a.y * 0.125f;
      v[u].z = xv.z + a.z * 0.125f; v[u].w = xv.w + a.w * 0.125f;
    }
  } else {
    int hw = (n - 1) >> 3, t = (n - 1) & 7;
    const float4* xt4 = (const float4*)(xt + (size_t)(b * 1568 + n - 1) * 768);
    const float4* rs4 = (const float4*)(rs + (size_t)((b * 8 + t) * 197 + 1 + hw) * 768);
#pragma unroll
    for (int u = 0; u < 3; ++u) {
      int j = l + 64 * u;
      float4 a = xt4[j], c = rs4[j];
      v[u].x = a.x + c.x; v[u].y = a.y + c.y; v[u].z = a.z + c.z; v[u].w = a.w + c.w;
    }
  }
  float4* xn4 = (float4*)(xn + (size_t)r * 768);
#pragma unroll
  for (int u = 0; u < 3; ++u) {
    xn4[l + 64 * u] = v[u];
    s += v[u].x + v[u].y + v[u].z + v[u].w;
    s2 += v[u].x * v[u].x + v[u].y * v[u].y + v[u].z * v[u].z + v[u].w * v[u].w;
  }
#pragma unroll
  for (int o = 1; o < 64; o <<= 1) { s += __shfl_xor(s, o); s2 += __shfl_xor(s2, o); }
  float mu = s * (1.f / 768.f);
  float rstd = rsqrtf(s2 * (1.f / 768.f) - mu * mu + 1e-5f);
  const float4* g4 = (const float4*)gam;
  const float4* b4 = (const float4*)bet;
  uint2* yr = (uint2*)(y + (size_t)r * 768);
#pragma unroll
  for (int u = 0; u < 3; ++u) {
    int j = l + 64 * u;
    float4 gg = g4[j], bb = b4[j];
    union { unsigned short h[4]; uint2 u2; } pk;
    pk.h[0] = bf16bits((v[u].x - mu) * rstd * gg.x + bb.x);
    pk.h[1] = bf16bits((v[u].y - mu) * rstd * gg.y + bb.y);
    pk.h[2] = bf16bits((v[u].z - mu) * rstd * gg.z + bb.z);
    pk.h[3] = bf16bits((v[u].w - mu) * rstd * gg.w + bb.w);
    yr[j] = pk.u2;
  }
}

// ============ GEMM 128x128, BK=32, ring-3 LDS, ONE barrier/step, counted vmcnt ============
template <int OUTBF16, int RES, int GELU>
__global__ __launch_bounds__(256, 3) void gemm_k(
    const bf16* __restrict__ X, const bf16* __restrict__ W,
    const float* __restrict__ bias, const float* __restrict__ resid,
    void* __restrict__ outp, int M, int N, int K) {
  constexpr int BUFB = 256 * 64;
  __shared__ __align__(16) char LDS[3 * BUFB];
  const int tid = threadIdx.x;
  const int w = tid >> 6, l = tid & 63;
  const int wr = w >> 1, wc = w & 1;
  const int lr = l & 15, lg = l >> 4;

  const int nwg = gridDim.x;
  const int orig = blockIdx.x;
  const int qd = nwg >> 3, rm = nwg & 7;
  const int xcd = orig & 7, lot = orig >> 3;
  const int swz = (xcd < rm ? xcd * (qd + 1) : rm * (qd + 1) + (xcd - rm) * qd) + lot;
  const int ntx = N >> 7;
  const int m0 = (swz / ntx) << 7, n0 = (swz % ntx) << 7;

  const char* pA[2]; const char* pB[2]; int dd[2];
#pragma unroll
  for (int i = 0; i < 2; ++i) {
    int d = (i * 256 + tid) * 16;
    int s = d ^ (((d >> 7) & 3) << 4);
    int r = s >> 6, cb = s & 63;
    int ga = m0 + r; if (ga >= M) ga = M - 1;
    pA[i] = (const char*)X + (size_t)ga * K * 2 + cb;
    pB[i] = (const char*)W + (size_t)(n0 + r) * K * 2 + cb;
    dd[i] = d;
  }

  auto stage = [&](int t, char* buf) {
    size_t ko = (size_t)t * 64;
    gl_lds16(pA[0] + ko, buf + dd[0]);
    gl_lds16(pA[1] + ko, buf + dd[1]);
    gl_lds16(pB[0] + ko, buf + 8192 + dd[0]);
    gl_lds16(pB[1] + ko, buf + 8192 + dd[1]);
  };

  f32x4 acc[4][4] = {};
  auto comp = [&](const char* Ab) {
    const char* Bb = Ab + 8192;
    bf16x8 af[4], bg[4];
#pragma unroll
    for (int mf = 0; mf < 4; ++mf) {
      int d = (wr * 64 + mf * 16 + lr) * 64 + lg * 16;
      af[mf] = *(const bf16x8*)(Ab + (d ^ (((d >> 7) & 3) << 4)));
    }
#pragma unroll
    for (int nf = 0; nf < 4; ++nf) {
      int d = (wc * 64 + nf * 16 + lr) * 64 + lg * 16;
      bg[nf] = *(const bf16x8*)(Bb + (d ^ (((d >> 7) & 3) << 4)));
    }
    __builtin_amdgcn_s_setprio(1);
#pragma unroll
    for (int mf = 0; mf < 4; ++mf)
#pragma unroll
      for (int nf = 0; nf < 4; ++nf)
        acc[mf][nf] = __builtin_amdgcn_mfma_f32_16x16x32_bf16(af[mf], bg[nf], acc[mf][nf], 0, 0, 0);
    __builtin_amdgcn_s_setprio(0);
  };

  const int nt = K >> 5;
  stage(0, LDS);
  stage(1, LDS + BUFB);
  asm volatile("s_waitcnt vmcnt(4)\n\ts_barrier" ::: "memory");
  int t = 0;
#define GSTEP(BC, BS)                                                                      \
  {                                                                                        \
    if (t + 2 < nt) stage(t + 2, LDS + (BS) * BUFB);                                       \
    comp(LDS + (BC) * BUFB);                                                               \
    if (t + 2 < nt)                                                                        \
      asm volatile("s_waitcnt vmcnt(4)\n\ts_barrier" ::: "memory");                        \
    else if (t + 1 < nt)                                                                   \
      asm volatile("s_waitcnt vmcnt(0)\n\ts_barrier" ::: "memory");                        \
    ++t;                                                                                   \
  }
  while (t < nt) { GSTEP(0, 2) GSTEP(1, 0) GSTEP(2, 1) }
#undef GSTEP

#pragma unroll
  for (int mf = 0; mf < 4; ++mf) {
    int rowb = m0 + wr * 64 + mf * 16 + lg * 4;
#pragma unroll
    for (int nf = 0; nf < 4; ++nf) {
      int col = n0 + wc * 64 + nf * 16 + lr;
      float bv = bias ? bias[col] : 0.f;
#pragma unroll
      for (int q = 0; q < 4; ++q) {
        int row = rowb + q;
        if (row < M) {
          float v = acc[mf][nf][q] + bv;
          if (GELU) v = 0.5f * v * (1.f + erff(v * 0.70710678118654752f));
          if (RES == 1) v += resid[(size_t)(row + row / 1568 + 1) * 768 + col];
          if (RES == 2) v += resid[(size_t)row * N + col];
          if (OUTBF16) ((bf16*)outp)[(size_t)row * N + col] = __float2bfloat16(v);
          else         ((float*)outp)[(size_t)row * N + col] = v;
        }
      }
    }
  }
}

// ============ GEMM 64x64, BK=32, 4 waves, ring-4 LDS, prefetch-3 ============
// For small-N (768) latency-bound GEMMs: max block parallelism.
template <int OUTBF16, int RES, int GELU>
__global__ __launch_bounds__(256, 4) void gemm64(
    const bf16* __restrict__ X, const bf16* __restrict__ W,
    const float* __restrict__ bias, const float* __restrict__ resid,
    void* __restrict__ outp, int M, int N, int K) {
  constexpr int BUFB = 128 * 64;                 // 8 KB per K-tile (A 64 rows + B 64 rows)
  __shared__ __align__(16) char LDS[4 * BUFB];   // 32 KB
  const int tid = threadIdx.x;
  const int wc = tid >> 6, l = tid & 63;
  const int lr = l & 15, lg = l >> 4;

  const int nwg = gridDim.x;
  const int orig = blockIdx.x;
  const int qd = nwg >> 3, rm = nwg & 7;
  const int xcd = orig & 7, lot = orig >> 3;
  const int swz = (xcd < rm ? xcd * (qd + 1) : rm * (qd + 1) + (xcd - rm) * qd) + lot;
  const int ntx = N >> 6;
  const int m0 = (swz / ntx) << 6, n0 = (swz % ntx) << 6;

  // chunk i=0 -> A (rows 0..63), i=1 -> B (rows 64..127); 1 load each per stage
  const char* pS[2]; int dd[2];
#pragma unroll
  for (int i = 0; i < 2; ++i) {
    int d = (i * 256 + tid) * 16;
    int s = d ^ (((d >> 7) & 3) << 4);           // XOR stays below row bit (6) -> row unchanged
    int r = s >> 6, cb = s & 63;
    if (i == 0) {
      int ga = m0 + r; if (ga >= M) ga = M - 1;
      pS[0] = (const char*)X + (size_t)ga * K * 2 + cb;
    } else {
      pS[1] = (const char*)W + (size_t)(n0 + (r - 64)) * K * 2 + cb;
    }
    dd[i] = d;
  }

  auto stage = [&](int t, char* buf) {
    size_t ko = (size_t)t * 64;
    gl_lds16(pS[0] + ko, buf + dd[0]);
    gl_lds16(pS[1] + ko, buf + dd[1]);
  };

  f32x4 acc[4] = {};
  auto comp = [&](const char* buf) {
    bf16x8 af[4], bg;
#pragma unroll
    for (int mf = 0; mf < 4; ++mf) {
      int d = (mf * 16 + lr) * 64 + lg * 16;
      af[mf] = *(const bf16x8*)(buf + (d ^ (((d >> 7) & 3) << 4)));
    }
    {
      int d = (64 + wc * 16 + lr) * 64 + lg * 16;
      bg = *(const bf16x8*)(buf + (d ^ (((d >> 7) & 3) << 4)));
    }
    __builtin_amdgcn_s_setprio(1);
#pragma unroll
    for (int mf = 0; mf < 4; ++mf)
      acc[mf] = __builtin_amdgcn_mfma_f32_16x16x32_bf16(af[mf], bg, acc[mf], 0, 0, 0);
    __builtin_amdgcn_s_setprio(0);
  };

  const int nt = K >> 5;
  stage(0, LDS);
  stage(1, LDS + BUFB);
  stage(2, LDS + 2 * BUFB);
  asm volatile("s_waitcnt vmcnt(4)\n\ts_barrier" ::: "memory");   // tile 0 landed
  int t = 0;
#define GSTEP(BC, BS)                                                                      \
  {                                                                                        \
    if (t + 3 < nt) stage(t + 3, LDS + (BS) * BUFB);                                       \
    comp(LDS + (BC) * BUFB);                                                               \
    if (t + 3 < nt)                                                                        \
      asm volatile("s_waitcnt vmcnt(4)\n\ts_barrier" ::: "memory");                        \
    else if (t + 2 < nt)                                                                   \
      asm volatile("s_waitcnt vmcnt(2)\n\ts_barrier" ::: "memory");                        \
    else if (t + 1 < nt)                                                                   \
      asm volatile("s_waitcnt vmcnt(0)\n\ts_barrier" ::: "memory");                        \
    ++t;                                                                                   \
  }
  while (t < nt) { GSTEP(0, 3) GSTEP(1, 0) GSTEP(2, 1) GSTEP(3, 2) }
#undef GSTEP

#pragma unroll
  for (int mf = 0; mf < 4; ++mf) {
    int rowb = m0 + mf * 16 + lg * 4;
    int col = n0 + wc * 16 + lr;
    float bv = bias ? bias[col] : 0.f;
#pragma unroll
    for (int q = 0; q < 4; ++q) {
      int row = rowb + q;
      if (row < M) {
        float v = acc[mf][q] + bv;
        if (GELU) v = 0.5f * v * (1.f + erff(v * 0.70710678118654752f));
        if (RES == 1) v += resid[(size_t)(row + row / 1568 + 1) * 768 + col];
        if (RES == 2) v += resid[(size_t)row * N + col];
        if (OUTBF16) ((bf16*)outp)[(size_t)row * N + col] = __float2bfloat16(v);
        else         ((float*)outp)[(size_t)row * N + col] = v;
      }
    }
  }
}

// ---------------- temporal attention: 784 seqs x 12 heads, T=8, D=64 ----------------
__global__ __launch_bounds__(256) void attn_t_k(const bf16* __restrict__ qkv,
                                                bf16* __restrict__ outp) {
  __shared__ float sh[4][3 * 8 * 68];
  const int wv = threadIdx.x >> 6, l = threadIdx.x & 63;
  const int g = blockIdx.x * 4 + wv;
  const int sq = g / 12, hd = g % 12;
  float* qs = sh[wv];
  float* ks = qs + 544;
  float* vs = qs + 1088;
  const bf16* base = qkv + (size_t)sq * 8 * 2304 + hd * 64;
  {
    int row = l >> 3, c8 = (l & 7) * 8;
    const bf16* rp = base + (size_t)row * 2304 + c8;
    bf16x8 qv = *(const bf16x8*)rp;
    bf16x8 kv = *(const bf16x8*)(rp + 768);
    bf16x8 vv = *(const bf16x8*)(rp + 1536);
    float* qd = qs + row * 68 + c8;
    float* kd = ks + row * 68 + c8;
    float* vd = vs + row * 68 + c8;
    float4 a, b;
    a.x = (float)qv[0]; a.y = (float)qv[1]; a.z = (float)qv[2]; a.w = (float)qv[3];
    b.x = (float)qv[4]; b.y = (float)qv[5]; b.z = (float)qv[6]; b.w = (float)qv[7];
    *(float4*)qd = a; *(float4*)(qd + 4) = b;
    a.x = (float)kv[0]; a.y = (float)kv[1]; a.z = (float)kv[2]; a.w = (float)kv[3];
    b.x = (float)kv[4]; b.y = (float)kv[5]; b.z = (float)kv[6]; b.w = (float)kv[7];
    *(float4*)kd = a; *(float4*)(kd + 4) = b;
    a.x = (float)vv[0]; a.y = (float)vv[1]; a.z = (float)vv[2]; a.w = (float)vv[3];
    b.x = (float)vv[4]; b.y = (float)vv[5]; b.z = (float)vv[6]; b.w = (float)vv[7];
    *(float4*)vd = a; *(float4*)(vd + 4) = b;
  }
  __builtin_amdgcn_wave_barrier();
  const int i = l >> 3, j = l & 7;
  float s = 0.f;
#pragma unroll
  for (int d = 0; d < 64; ++d) s += qs[i * 68 + d] * ks[j * 68 + d];
  s *= 0.125f;
  float m = s;
  m = fmaxf(m, __shfl_xor(m, 1));
  m = fmaxf(m, __shfl_xor(m, 2));
  m = fmaxf(m, __shfl_xor(m, 4));
  float p = __expf(s - m);
  float sum = p;
  sum += __shfl_xor(sum, 1);
  sum += __shfl_xor(sum, 2);
  sum += __shfl_xor(sum, 4);
  p /= sum;
  float pr[8];
#pragma unroll
  for (int jj = 0; jj < 8; ++jj) pr[jj] = __shfl(p, i * 8 + jj);
  bf16* op = outp + (size_t)(sq * 8) * 768 + hd * 64;
#pragma unroll
  for (int u = 0; u < 8; ++u) {
    int c = j + 8 * u;
    float o = 0.f;
#pragma unroll
    for (int jj = 0; jj < 8; ++jj) o += pr[jj] * vs[jj * 68 + c];
    op[(size_t)i * 768 + c] = __float2bfloat16(o);
  }
}

// ---------------- build Vt[384][64][224] from spatial qkv ----------------
__global__ __launch_bounds__(256) void build_vt_k(const bf16* __restrict__ qkv,
                                                  bf16* __restrict__ vt) {
  const int sq = blockIdx.x / 12, hd = blockIdx.x % 12;
  const bf16* vsrc = qkv + (size_t)sq * 197 * 2304 + 1536 + hd * 64;
  bf16* dst = vt + (size_t)blockIdx.x * 64 * 224;
  for (int idx = threadIdx.x; idx < 197 * 64; idx += 256) {
    int j = idx >> 6, d = idx & 63;
    dst[d * 224 + j] = vsrc[(size_t)j * 2304 + d];
  }
}

// ---------------- spatial attention: 32 seqs x 12 heads, N=197, D=64 ----------------
__global__ __launch_bounds__(256) void attn_s_k(
    const bf16* __restrict__ qkv, const bf16* __restrict__ vt,
    bf16* __restrict__ outp) {
  __shared__ __align__(16) bf16 P[4][16 * 232];
  const int wv = threadIdx.x >> 6, l = threadIdx.x & 63;
  const int sq = blockIdx.x / 12, hd = blockIdx.x % 12;
  const int lr = l & 15, lg = l >> 4;
  bf16* Pw = P[wv];
#pragma unroll
  for (int idx = 0; idx < 4; ++idx) {
    int e = idx * 64 + l;
    Pw[(e >> 4) * 232 + 208 + (e & 15)] = __float2bfloat16(0.f);
  }
  const bf16* qbase = qkv + (size_t)sq * 197 * 2304 + hd * 64;
  const bf16* kbase = qbase + 768;
  const bf16* vbase = vt + (size_t)blockIdx.x * 64 * 224;
  for (int qt = wv; qt < 13; qt += 4) {
    int q0 = qt * 16;
    int qrow = q0 + lr; if (qrow > 196) qrow = 196;
    bf16x8 qa0 = *(const bf16x8*)(qbase + (size_t)qrow * 2304 + lg * 8);
    bf16x8 qa1 = *(const bf16x8*)(qbase + (size_t)qrow * 2304 + 32 + lg * 8);
    f32x4 sacc[13];
#pragma unroll
    for (int jt = 0; jt < 13; ++jt) {
      const bf16* kp = kbase + (size_t)(jt * 16 + lr) * 2304;
      bf16x8 kb0 = *(const bf16x8*)(kp + lg * 8);
      bf16x8 kb1 = *(const bf16x8*)(kp + 32 + lg * 8);
      f32x4 z = {};
      z = __builtin_amdgcn_mfma_f32_16x16x32_bf16(qa0, kb0, z, 0, 0, 0);
      z = __builtin_amdgcn_mfma_f32_16x16x32_bf16(qa1, kb1, z, 0, 0, 0);
      sacc[jt] = z;
    }
#pragma unroll
    for (int jt = 0; jt < 13; ++jt) {
      bool valid = (jt * 16 + lr) < 197;
#pragma unroll
      for (int q = 0; q < 4; ++q)
        sacc[jt][q] = valid ? sacc[jt][q] * 0.125f : -3e38f;
    }
    float inv[4];
#pragma unroll
    for (int q = 0; q < 4; ++q) {
      float m = -3e38f;
#pragma unroll
      for (int jt = 0; jt < 13; ++jt) m = fmaxf(m, sacc[jt][q]);
      m = fmaxf(m, __shfl_xor(m, 1));
      m = fmaxf(m, __shfl_xor(m, 2));
      m = fmaxf(m, __shfl_xor(m, 4));
      m = fmaxf(m, __shfl_xor(m, 8));
      float ssum = 0.f;
#pragma unroll
      for (int jt = 0; jt < 13; ++jt) {
        float p = __expf(sacc[jt][q] - m);
        sacc[jt][q] = p;
        ssum += p;
      }
      ssum += __shfl_xor(ssum, 1);
      ssum += __shfl_xor(ssum, 2);
      ssum += __shfl_xor(ssum, 4);
      ssum += __shfl_xor(ssum, 8);
      inv[q] = 1.f / ssum;
    }
#pragma unroll
    for (int jt = 0; jt < 13; ++jt)
#pragma unroll
      for (int q = 0; q < 4; ++q)
        Pw[(lg * 4 + q) * 232 + jt * 16 + lr] = __float2bfloat16(sacc[jt][q]);
    __builtin_amdgcn_wave_barrier();
    f32x4 oacc[4] = {};
#pragma unroll
    for (int j7 = 0; j7 < 7; ++j7) {
      bf16x8 pa = *(const bf16x8*)(Pw + lr * 232 + j7 * 32 + lg * 8);
#pragma unroll
      for (int n = 0; n < 4; ++n) {
        bf16x8 vb = *(const bf16x8*)(vbase + (size_t)(n * 16 + lr) * 224 + j7 * 32 + lg * 8);
        oacc[n] = __builtin_amdgcn_mfma_f32_16x16x32_bf16(pa, vb, oacc[n], 0, 0, 0);
      }
    }
    __builtin_amdgcn_wave_barrier();
#pragma unroll
    for (int n = 0; n < 4; ++n)
#pragma unroll
      for (int q = 0; q < 4; ++q) {
        int orow = q0 + lg * 4 + q;
        if (orow < 197)
          outp[(size_t)(sq * 197 + orow) * 768 + hd * 64 + n * 16 + lr] =
              __float2bfloat16(oacc[n][q] * inv[q]);
      }
  }
}

extern "C" void kernel_launch(void* const* d_in, const int* in_sizes, int n_in,
                              void* d_out, int out_size, void* d_ws, size_t ws_size,
                              hipStream_t stream) {
  (void)in_sizes; (void)n_in; (void)out_size; (void)ws_size;
  const float* x        = (const float*)d_in[0];
  const float* ln_t_g   = (const float*)d_in[1];
  const float* ln_t_b   = (const float*)d_in[2];
  const float* t_qkv_w  = (const float*)d_in[3];
  const float* t_qkv_b  = (const float*)d_in[4];
  const float* t_proj_w = (const float*)d_in[5];
  const float* t_proj_b = (const float*)d_in[6];
  const float* t_fc_w   = (const float*)d_in[7];
  const float* t_fc_b   = (const float*)d_in[8];
  const float* ln1_g    = (const float*)d_in[9];
  const float* ln1_b    = (const float*)d_in[10];
  const float* s_qkv_w  = (const float*)d_in[11];
  const float* s_qkv_b  = (const float*)d_in[12];
  const float* s_proj_w = (const float*)d_in[13];
  const float* s_proj_b = (const float*)d_in[14];
  const float* ln2_g    = (const float*)d_in[15];
  const float* ln2_b    = (const float*)d_in[16];
  const float* fc1_w    = (const float*)d_in[17];
  const float* fc1_b    = (const float*)d_in[18];
  const float* fc2_w    = (const float*)d_in[19];
  const float* fc2_b    = (const float*)d_in[20];

  char* ws = (char*)d_ws;
  size_t o = 0;
  auto alloc = [&](size_t bytes) { size_t r = o; o += (bytes + 255) & ~(size_t)255; return r; };
  bf16* wqkvt  = (bf16*)(ws + alloc((size_t)2304 * 768 * 2));
  bf16* wqkvs  = (bf16*)(ws + alloc((size_t)2304 * 768 * 2));
  bf16* wprojs = (bf16*)(ws + alloc((size_t)768 * 768 * 2));
  bf16* wfct   = (bf16*)(ws + alloc((size_t)768 * 768 * 2));
  bf16* wpT    = (bf16*)(ws + alloc((size_t)768 * 768 * 2));
  bf16* wcomb  = (bf16*)(ws + alloc((size_t)768 * 768 * 2));
  float* bcomb = (float*)(ws + alloc((size_t)768 * 4));
  bf16* wfc1   = (bf16*)(ws + alloc((size_t)3072 * 768 * 2));
  bf16* wfc2   = (bf16*)(ws + alloc((size_t)768 * 3072 * 2));
  bf16* ybuf   = (bf16*)(ws + alloc((size_t)6400 * 768 * 2));
  char* big    = ws + alloc((size_t)6400 * 3072 * 2);      // qkv, later h1
  bf16* qkvb   = (bf16*)big;
  bf16* h1     = (bf16*)big;
  bf16* abuf   = (bf16*)(ws + alloc((size_t)6400 * 768 * 2));
  char* slotS  = ws + alloc((size_t)6304 * 768 * 4);       // vt / rs (disjoint lifetimes)
  bf16* vtb    = (bf16*)slotS;
  float* rsb   = (float*)slotS;
  float* xtb   = (float*)(ws + alloc((size_t)6272 * 768 * 4));
  float* xnb   = (float*)(ws + alloc((size_t)6276 * 768 * 4));

  // weights -> bf16 (merged) + transposed proj_t + combined temporal proj*fc
  {
    CvtSeg s0{(const float4*)t_qkv_w, (uint2*)wqkvt, 442368};
    CvtSeg s1{(const float4*)s_qkv_w, (uint2*)wqkvs, 442368 + 442368};
    CvtSeg s2{(const float4*)s_proj_w, (uint2*)wprojs, 884736 + 147456};
    CvtSeg s3{(const float4*)t_fc_w, (uint2*)wfct, 1032192 + 147456};
    CvtSeg s4{(const float4*)fc1_w, (uint2*)wfc1, 1179648 + 589824};
    CvtSeg s5{(const float4*)fc2_w, (uint2*)wfc2, 1769472 + 589824};
    cvt_all_k<<<(2359296 + 255) / 256, 256, 0, stream>>>(s0, s1, s2, s3, s4, s5);
  }
  cvt_t_k<<<2304, 256, 0, stream>>>(t_proj_w, wpT);
  bcomb_k<<<192, 256, 0, stream>>>(t_fc_w, t_proj_b, t_fc_b, bcomb);
  // Wcomb[j][k] = sum_i Wf[j][i] * Wp[i][k]
  gemm64<1, 0, 0><<<144, 256, 0, stream>>>(wfct, wpT, nullptr, nullptr, wcomb, 768, 768, 768);

  // temporal branch
  ln_k<<<1568, 256, 0, stream>>>(x, nullptr, ln_t_g, ln_t_b, ybuf, 6272, 0);
  gemm_k<1, 0, 0><<<882, 256, 0, stream>>>(ybuf, wqkvt, t_qkv_b, nullptr, qkvb, 6272, 2304, 768);
  attn_t_k<<<2352, 256, 0, stream>>>(qkvb, abuf);
  gemm64<0, 1, 0><<<1176, 256, 0, stream>>>(abuf, wcomb, bcomb, x, xtb, 6272, 768, 768);

  // spatial branch
  ln_k<<<1576, 256, 0, stream>>>(x, xtb, ln1_g, ln1_b, ybuf, 6304, 1);
  gemm_k<1, 0, 0><<<900, 256, 0, stream>>>(ybuf, wqkvs, s_qkv_b, nullptr, qkvb, 6304, 2304, 768);
  build_vt_k<<<384, 256, 0, stream>>>(qkvb, vtb);
  attn_s_k<<<384, 256, 0, stream>>>(qkvb, vtb, abuf);
  gemm64<0, 0, 0><<<1188, 256, 0, stream>>>(abuf, wprojs, s_proj_b, nullptr, rsb, 6304, 768, 768);

  // combine residuals + LN2 (fused)
  combine_ln_k<<<1569, 256, 0, stream>>>(x, xtb, rsb, ln2_g, ln2_b, xnb, ybuf);

  // MLP
  gemm_k<1, 0, 1><<<1200, 256, 0, stream>>>(ybuf, wfc1, fc1_b, nullptr, h1, 6276, 3072, 768);
  gemm64<0, 2, 0><<<1188, 256, 0, stream>>>(h1, wfc2, fc2_b, xnb, (float*)d_out, 6276, 768, 3072);
}